// Round 8
// baseline (723.382 us; speedup 1.0000x reference)
//
#include <hip/hip_runtime.h>
#include <math.h>

typedef __bf16 bf16x8 __attribute__((ext_vector_type(8)));
typedef float f32x4 __attribute__((ext_vector_type(4)));

#define MTOT 32768   // B*N
#define DD   1024
#define NSEQ 4096
#define BB   8

__device__ __forceinline__ void async16(const void* gp, void* lp) {
  __builtin_amdgcn_global_load_lds(
      (__attribute__((address_space(1))) void*)(const_cast<void*>(gp)),
      (__attribute__((address_space(3))) void*)(lp), 16, 0, 0);
}

__device__ __forceinline__ unsigned short f2bf(float f) {
  union { float f; unsigned int u; } v; v.f = f;
  unsigned int r = v.u + 0x7fffu + ((v.u >> 16) & 1u);
  return (unsigned short)(r >> 16);
}
__device__ __forceinline__ float bf2f(unsigned short u) {
  union { unsigned int u; float f; } v; v.u = ((unsigned int)u) << 16; return v.f;
}

// DS byte address of an LDS object (compiler-sanctioned addrspacecast).
__device__ __forceinline__ unsigned lds_off(void* p) {
  return (unsigned)(unsigned long long)
      (__attribute__((address_space(3))) void*)p;
}
// Inline-asm ds_read_b128 with compile-time offset immediate.
// Rule-18: every consumer cluster gated by explicit lgkmcnt + sched_barrier(0).
#define DSRI(dst, base, off) \
  asm volatile("ds_read_b128 %0, %1 offset:" #off : "=v"(dst) : "v"(base))

#define MFMA_ __builtin_amdgcn_mfma_f32_16x16x32_bf16

// ---------------- fp32 -> bf16 convert (x) ----------------
__global__ void cvt_bf16(const float* __restrict__ in, unsigned short* __restrict__ out, int n) {
  int i = (blockIdx.x * blockDim.x + threadIdx.x) * 8;
  if (i >= n) return;
  float4 a = *(const float4*)(in + i);
  float4 b = *(const float4*)(in + i + 4);
  ushort4 o0, o1;
  o0.x = f2bf(a.x); o0.y = f2bf(a.y); o0.z = f2bf(a.z); o0.w = f2bf(a.w);
  o1.x = f2bf(b.x); o1.y = f2bf(b.y); o1.z = f2bf(b.z); o1.w = f2bf(b.w);
  *(ushort4*)(out + i) = o0;
  *(ushort4*)(out + i + 4) = o1;
}

// ---------------- weights: 4 matrices in one dispatch ----------------
__global__ void cvt_w(const float* __restrict__ w0, const float* __restrict__ w1,
                      const float* __restrict__ w2, const float* __restrict__ w3,
                      unsigned short* __restrict__ out) {
  int z = blockIdx.y;
  const float* in = (z == 0) ? w0 : (z == 1) ? w1 : (z == 2) ? w2 : w3;
  int i = (blockIdx.x * blockDim.x + threadIdx.x) * 8;
  float4 a = *(const float4*)(in + i);
  float4 b = *(const float4*)(in + i + 4);
  ushort4 o0, o1;
  o0.x = f2bf(a.x); o0.y = f2bf(a.y); o0.z = f2bf(a.z); o0.w = f2bf(a.w);
  o1.x = f2bf(b.x); o1.y = f2bf(b.y); o1.z = f2bf(b.z); o1.w = f2bf(b.w);
  unsigned short* o = out + (size_t)z * DD * DD;
  *(ushort4*)(o + i) = o0;
  *(ushort4*)(o + i + 4) = o1;
}

// Stage one 128x64 bf16 half-tile into a LINEAR LDS region via global_load_lds.
// T2 swizzle on the GLOBAL SOURCE side (rule 21): LDS slot s of row r receives
// global slot s ^ (r&7); the swizzled ds_reads apply the same XOR.
template<int LDG>
__device__ __forceinline__ void stage_half(const unsigned short* __restrict__ g,
                                           int row0, int k0,
                                           unsigned short* lds, int tid) {
#pragma unroll
  for (int l = 0; l < 2; ++l) {
    int u = l * 512 + tid;           // 16B unit within the 16 KiB half-tile
    int r = u >> 3;                  // row within half (0..127)
    int sl = (u & 7) ^ (r & 7);      // pre-swizzled source slot
    async16(g + (size_t)(row0 + r) * LDG + k0 + sl * 8, (char*)lds + u * 16);
  }
}

// ---------------- fused V GEMM (256x128 tile, BK=64): Vr,Vi in one K-loop ------
// A staged once per tile, multiplied against BOTH Wvr and Wvi; GLU in-register.
// Wave grid 4x2; wave owns 64x64 per weight. acc: 2x 16 f32x4 = 128 AGPR.
__global__ __launch_bounds__(512, 2) void proj_v(
    const unsigned short* __restrict__ xb,
    const unsigned short* __restrict__ Wb,   // slot0 = Wvr, slot1 = Wvi
    const float* __restrict__ bvr, const float* __restrict__ bvi,
    unsigned short* __restrict__ oV) {
  // buffer = A 256x64 (32KB) + Bvr 128x64 (16KB) + Bvi (16KB) = 64KB; dbuf 128KB
  __shared__ __align__(16) unsigned short smem[65536];

  const int bx = blockIdx.x;
  const int swz = (bx & 7) * 128 + (bx >> 3);  // bijective XCD swizzle (1024=8*128)
  const int m0 = (swz >> 3) * 256;
  const int n0 = (swz & 7) * 128;
  const unsigned short* Wr = Wb;
  const unsigned short* Wi = Wb + (size_t)DD * DD;

  const int tid = threadIdx.x;
  const int w = tid >> 6, lane = tid & 63;
  const int wrow = w >> 1, wcol = w & 1;       // 4x2 wave grid
  const int lq = lane >> 4, lr = lane & 15;
  const int sx = lr & 7;
  const int arow0 = wrow * 64 + lr;
  const int brow0 = wcol * 64 + lr;

  f32x4 accr[4][4], acci[4][4];
#pragma unroll
  for (int i = 0; i < 4; i++)
#pragma unroll
    for (int j = 0; j < 4; j++) { accr[i][j] = (f32x4)(0.f); acci[i][j] = (f32x4)(0.f); }

  const int NT = 16;  // K=1024 / BK=64

  const unsigned sbase = lds_off(smem);
  const unsigned sw0 = (unsigned)((lq ^ sx) << 4);
  const unsigned sw1 = (unsigned)(((4 | lq) ^ sx) << 4);
  unsigned aA0 = sbase + arow0 * 128 + sw0;
  unsigned aA1 = sbase + arow0 * 128 + sw1;
  unsigned aR0 = sbase + 32768 + brow0 * 128 + sw0;
  unsigned aR1 = sbase + 32768 + brow0 * 128 + sw1;
  unsigned aI0 = sbase + 49152 + brow0 * 128 + sw0;
  unsigned aI1 = sbase + 49152 + brow0 * 128 + sw1;

  // prologue: A(0) h0,h1 ; Bvr(0),Bvi(0) -> buf0 ; Bvr(1),Bvi(1) -> buf1 (12 insts)
  stage_half<1024>(xb, m0,       0,  smem,                  tid);
  stage_half<1024>(xb, m0 + 128, 0,  smem + 8192,           tid);
  stage_half<1024>(Wr, n0,       0,  smem + 16384,          tid);
  stage_half<1024>(Wi, n0,       0,  smem + 24576,          tid);
  stage_half<1024>(Wr, n0,       64, smem + 32768 + 16384,  tid);
  stage_half<1024>(Wi, n0,       64, smem + 32768 + 24576,  tid);
  asm volatile("s_waitcnt vmcnt(4)" ::: "memory");  // tile0 landed, B(1) in flight
  __builtin_amdgcn_s_barrier();

  for (int t = 0; t < NT; ++t) {
    // ---- all 24 reads of tile t (buffer validated by previous end-barrier) ----
    bf16x8 aF[4][2], bR[4][2], bI[4][2];
    DSRI(aF[0][0], aA0, 0);    DSRI(aF[0][1], aA1, 0);
    DSRI(bR[0][0], aR0, 0);    DSRI(bR[0][1], aR1, 0);
    DSRI(bR[1][0], aR0, 2048); DSRI(bR[1][1], aR1, 2048);
    DSRI(bR[2][0], aR0, 4096); DSRI(bR[2][1], aR1, 4096);
    DSRI(bR[3][0], aR0, 6144); DSRI(bR[3][1], aR1, 6144);
    DSRI(aF[1][0], aA0, 2048); DSRI(aF[1][1], aA1, 2048);
    DSRI(aF[2][0], aA0, 4096); DSRI(aF[2][1], aA1, 4096);
    DSRI(aF[3][0], aA0, 6144); DSRI(aF[3][1], aA1, 6144);
    DSRI(bI[0][0], aI0, 0);    DSRI(bI[0][1], aI1, 0);
    DSRI(bI[1][0], aI0, 2048); DSRI(bI[1][1], aI1, 2048);
    DSRI(bI[2][0], aI0, 4096); DSRI(bI[2][1], aI1, 4096);
    DSRI(bI[3][0], aI0, 6144); DSRI(bI[3][1], aI1, 6144);
    // stage A(t+1) (its old content A(t-1) fully read before t-1's mid barrier)
    if (t + 1 < NT) {
      stage_half<1024>(xb, m0,       (t + 1) * 64, smem + ((t + 1) & 1) * 32768, tid);
      stage_half<1024>(xb, m0 + 128, (t + 1) * 64, smem + ((t + 1) & 1) * 32768 + 8192, tid);
    }
    // ---- Vr MFMAs ----
    asm volatile("s_waitcnt lgkmcnt(14)" ::: "memory");  // aF[0] + all bR landed
    __builtin_amdgcn_sched_barrier(0);
    __builtin_amdgcn_s_setprio(1);
#pragma unroll
    for (int nj = 0; nj < 4; ++nj) {
      accr[0][nj] = MFMA_(aF[0][0], bR[nj][0], accr[0][nj], 0, 0, 0);
      accr[0][nj] = MFMA_(aF[0][1], bR[nj][1], accr[0][nj], 0, 0, 0);
    }
    asm volatile("s_waitcnt lgkmcnt(8)" ::: "memory");   // aF[1..3] landed
    __builtin_amdgcn_sched_barrier(0);
#pragma unroll
    for (int mi = 1; mi < 4; ++mi)
#pragma unroll
      for (int nj = 0; nj < 4; ++nj) {
        accr[mi][nj] = MFMA_(aF[mi][0], bR[nj][0], accr[mi][nj], 0, 0, 0);
        accr[mi][nj] = MFMA_(aF[mi][1], bR[nj][1], accr[mi][nj], 0, 0, 0);
      }
    __builtin_amdgcn_s_setprio(0);
    asm volatile("s_waitcnt lgkmcnt(0)" ::: "memory");   // bI landed; ALL reads drained
    __builtin_amdgcn_sched_barrier(0);
    __builtin_amdgcn_s_barrier();   // block-wide: everyone done reading buf[t&1]
    // stage B(t+2) over B(t) region — safe now
    if (t + 2 < NT) {
      stage_half<1024>(Wr, n0, (t + 2) * 64, smem + (t & 1) * 32768 + 16384, tid);
      stage_half<1024>(Wi, n0, (t + 2) * 64, smem + (t & 1) * 32768 + 24576, tid);
    }
    // ---- Vi MFMAs: pure register, overlaps staging DMA ----
    __builtin_amdgcn_s_setprio(1);
#pragma unroll
    for (int mi = 0; mi < 4; ++mi)
#pragma unroll
      for (int nj = 0; nj < 4; ++nj) {
        acci[mi][nj] = MFMA_(aF[mi][0], bI[nj][0], acci[mi][nj], 0, 0, 0);
        acci[mi][nj] = MFMA_(aF[mi][1], bI[nj][1], acci[mi][nj], 0, 0, 0);
      }
    __builtin_amdgcn_s_setprio(0);
    __builtin_amdgcn_sched_barrier(0);
    if (t < NT - 2)       asm volatile("s_waitcnt vmcnt(4)" ::: "memory");
    else if (t == NT - 2) asm volatile("s_waitcnt vmcnt(0)" ::: "memory");
    __builtin_amdgcn_s_barrier();

    aA0 ^= 65536u; aA1 ^= 65536u; aR0 ^= 65536u; aR1 ^= 65536u;
    aI0 ^= 65536u; aI1 ^= 65536u;
  }

  // fused GLU epilogue — numerics identical to the old store+glu path
#pragma unroll
  for (int nj = 0; nj < 4; ++nj) {
    int col = n0 + wcol * 64 + nj * 16 + lr;
    float br_ = bvr[col], bi_ = bvi[col];
#pragma unroll
    for (int mi = 0; mi < 4; ++mi) {
      int rowb = m0 + wrow * 64 + mi * 16 + lq * 4;
#pragma unroll
      for (int r = 0; r < 4; ++r) {
        float vr = bf2f(f2bf(accr[mi][nj][r] + br_));
        float vi = bf2f(f2bf(acci[mi][nj][r] + bi_));
        float g;
        if (vi > 10.f) g = 1.f;
        else { float tt = __expf(vi); float u = tt * (tt + 2.f); g = u / (u + 2.f); }
        oV[(size_t)(rowb + r) * DD + col] = f2bf(vr * g);
      }
    }
  }
}

// ---------------- K/Q projection (256^2 tile, BK=64, 2-phase/tile) -------------
// z: 0 = K, 1 = Q. Transposed epilogue + sumsq. (round-4 known-good structure)
__global__ __launch_bounds__(512, 2) void proj_kq(
    const unsigned short* __restrict__ xb,
    const unsigned short* __restrict__ Wb,
    const float* __restrict__ bk,  const float* __restrict__ bq,
    unsigned short* __restrict__ Kt,  unsigned short* __restrict__ Qt,
    float* __restrict__ rnacc) {
  __shared__ __align__(16) unsigned short smem[65536];

  const int bx = blockIdx.x;
  const int swz = (bx & 7) * 64 + (bx >> 3);   // bijective XCD swizzle (512 = 8*64)
  const int m0 = (swz >> 2) * 256;
  const int n0 = (swz & 3) * 256;
  const int z = blockIdx.z;
  const unsigned short* W = Wb + (size_t)(2 + z) * DD * DD;
  const float* bias = (z == 0) ? bk : bq;

  const int tid = threadIdx.x;
  const int w = tid >> 6, lane = tid & 63;
  const int wr = w >> 2, wc = w & 3;
  const int lq = lane >> 4, lr = lane & 15;
  const int sx = lr & 7;
  const int arow0 = wr * 128 + lr;
  const int brow0 = wc * 64 + lr;

  f32x4 acc[8][4];
#pragma unroll
  for (int i = 0; i < 8; i++)
#pragma unroll
    for (int j = 0; j < 4; j++) acc[i][j] = (f32x4)(0.f);

  const int NT = 16;

  const unsigned sbase = lds_off(smem);
  const unsigned sw0 = (unsigned)((lq ^ sx) << 4);
  const unsigned sw1 = (unsigned)(((4 | lq) ^ sx) << 4);
  unsigned aA0 = sbase + arow0 * 128 + sw0;
  unsigned aA1 = sbase + arow0 * 128 + sw1;
  unsigned aB0 = sbase + 32768 + brow0 * 128 + sw0;
  unsigned aB1 = sbase + 32768 + brow0 * 128 + sw1;

  stage_half<1024>(xb, m0,       0,  smem,                     tid);
  stage_half<1024>(xb, m0 + 128, 0,  smem + 8192,              tid);
  stage_half<1024>(W,  n0,       0,  smem + 16384,             tid);
  stage_half<1024>(W,  n0 + 128, 0,  smem + 16384 + 8192,      tid);
  stage_half<1024>(W,  n0,       64, smem + 32768 + 16384,     tid);
  stage_half<1024>(W,  n0 + 128, 64, smem + 32768 + 16384 + 8192, tid);
  asm volatile("s_waitcnt vmcnt(4)" ::: "memory");
  __builtin_amdgcn_s_barrier();

  for (int t = 0; t < NT; ++t) {
    bf16x8 bfr[4][2], aL[4][2];
    DSRI(aL[0][0], aA0, 0);    DSRI(aL[0][1], aA1, 0);
    DSRI(bfr[0][0], aB0, 0);    DSRI(bfr[0][1], aB1, 0);
    DSRI(bfr[1][0], aB0, 2048); DSRI(bfr[1][1], aB1, 2048);
    DSRI(bfr[2][0], aB0, 4096); DSRI(bfr[2][1], aB1, 4096);
    DSRI(bfr[3][0], aB0, 6144); DSRI(bfr[3][1], aB1, 6144);
    DSRI(aL[1][0], aA0, 2048); DSRI(aL[1][1], aA1, 2048);
    DSRI(aL[2][0], aA0, 4096); DSRI(aL[2][1], aA1, 4096);
    DSRI(aL[3][0], aA0, 6144); DSRI(aL[3][1], aA1, 6144);
    if (t + 1 < NT) {
      stage_half<1024>(xb, m0,       (t + 1) * 64, smem + ((t + 1) & 1) * 32768, tid);
      stage_half<1024>(xb, m0 + 128, (t + 1) * 64, smem + ((t + 1) & 1) * 32768 + 8192, tid);
    }
    __builtin_amdgcn_s_barrier();
    asm volatile("s_waitcnt lgkmcnt(6)" ::: "memory");
    __builtin_amdgcn_sched_barrier(0);
    __builtin_amdgcn_s_setprio(1);
#pragma unroll
    for (int nj = 0; nj < 4; ++nj) {
      acc[0][nj] = MFMA_(aL[0][0], bfr[nj][0], acc[0][nj], 0, 0, 0);
      acc[0][nj] = MFMA_(aL[0][1], bfr[nj][1], acc[0][nj], 0, 0, 0);
    }
    asm volatile("s_waitcnt lgkmcnt(0)" ::: "memory");
    __builtin_amdgcn_sched_barrier(0);
#pragma unroll
    for (int mi = 1; mi < 4; ++mi)
#pragma unroll
      for (int nj = 0; nj < 4; ++nj) {
        acc[mi][nj] = MFMA_(aL[mi][0], bfr[nj][0], acc[mi][nj], 0, 0, 0);
        acc[mi][nj] = MFMA_(aL[mi][1], bfr[nj][1], acc[mi][nj], 0, 0, 0);
      }
    __builtin_amdgcn_s_setprio(0);
    __builtin_amdgcn_sched_barrier(0);
    __builtin_amdgcn_s_barrier();

    bf16x8 aH[4][2];
    DSRI(aH[0][0], aA0, 8192);  DSRI(aH[0][1], aA1, 8192);
    DSRI(aH[1][0], aA0, 10240); DSRI(aH[1][1], aA1, 10240);
    DSRI(aH[2][0], aA0, 12288); DSRI(aH[2][1], aA1, 12288);
    DSRI(aH[3][0], aA0, 14336); DSRI(aH[3][1], aA1, 14336);
    if (t + 2 < NT) {
      stage_half<1024>(W, n0,       (t + 2) * 64, smem + (t & 1) * 32768 + 16384, tid);
      stage_half<1024>(W, n0 + 128, (t + 2) * 64, smem + (t & 1) * 32768 + 16384 + 8192, tid);
    }
    __builtin_amdgcn_s_barrier();
    asm volatile("s_waitcnt lgkmcnt(4)" ::: "memory");
    __builtin_amdgcn_sched_barrier(0);
    __builtin_amdgcn_s_setprio(1);
#pragma unroll
    for (int mi = 0; mi < 2; ++mi)
#pragma unroll
      for (int nj = 0; nj < 4; ++nj) {
        acc[4 + mi][nj] = MFMA_(aH[mi][0], bfr[nj][0], acc[4 + mi][nj], 0, 0, 0);
        acc[4 + mi][nj] = MFMA_(aH[mi][1], bfr[nj][1], acc[4 + mi][nj], 0, 0, 0);
      }
    asm volatile("s_waitcnt lgkmcnt(0)" ::: "memory");
    __builtin_amdgcn_sched_barrier(0);
#pragma unroll
    for (int mi = 2; mi < 4; ++mi)
#pragma unroll
      for (int nj = 0; nj < 4; ++nj) {
        acc[4 + mi][nj] = MFMA_(aH[mi][0], bfr[nj][0], acc[4 + mi][nj], 0, 0, 0);
        acc[4 + mi][nj] = MFMA_(aH[mi][1], bfr[nj][1], acc[4 + mi][nj], 0, 0, 0);
      }
    __builtin_amdgcn_s_setprio(0);
    __builtin_amdgcn_sched_barrier(0);
    if (t < NT - 2)       asm volatile("s_waitcnt vmcnt(4)" ::: "memory");
    else if (t == NT - 2) asm volatile("s_waitcnt vmcnt(0)" ::: "memory");
    __builtin_amdgcn_s_barrier();

    aA0 ^= 65536u; aA1 ^= 65536u; aB0 ^= 65536u; aB1 ^= 65536u;
  }

  // transposed epilogue: two 128-col halves through LDS, coalesced [b][d][n] store + sumsq
  {
    unsigned short* outp = (z == 0) ? Kt : Qt;
    const int b = m0 >> 12;
    const int nbase = m0 & 4095;
    float* racc = rnacc + z * (BB * DD) + b * DD;
    unsigned short* T = smem;
    const int SP2 = 264;
#pragma unroll
    for (int ch = 0; ch < 2; ++ch) {
      if ((wc >> 1) == ch) {
#pragma unroll
        for (int nj = 0; nj < 4; ++nj) {
          int cloc = (wc & 1) * 64 + nj * 16 + lr;
          float bv = bias[n0 + ch * 128 + cloc];
#pragma unroll
          for (int mrep = 0; mrep < 8; ++mrep) {
            int rowb = wr * 128 + mrep * 16 + lq * 4;
            ushort4 pk;
            pk.x = f2bf(acc[mrep][nj][0] + bv); pk.y = f2bf(acc[mrep][nj][1] + bv);
            pk.z = f2bf(acc[mrep][nj][2] + bv); pk.w = f2bf(acc[mrep][nj][3] + bv);
            *(ushort4*)(T + cloc * SP2 + rowb) = pk;
          }
        }
      }
      __syncthreads();
#pragma unroll
      for (int p = 0; p < 8; ++p) {
        int dl = p * 16 + (tid >> 5);
        int nc = (tid & 31) * 8;
        ushort4 v0 = *(const ushort4*)(T + dl * SP2 + nc);
        ushort4 v1 = *(const ushort4*)(T + dl * SP2 + nc + 4);
        int d = n0 + ch * 128 + dl;
        *(ushort4*)(outp + (size_t)(b * DD + d) * NSEQ + nbase + nc)     = v0;
        *(ushort4*)(outp + (size_t)(b * DD + d) * NSEQ + nbase + nc + 4) = v1;
        float s = bf2f(v0.x)*bf2f(v0.x) + bf2f(v0.y)*bf2f(v0.y) + bf2f(v0.z)*bf2f(v0.z) + bf2f(v0.w)*bf2f(v0.w)
                + bf2f(v1.x)*bf2f(v1.x) + bf2f(v1.y)*bf2f(v1.y) + bf2f(v1.z)*bf2f(v1.z) + bf2f(v1.w)*bf2f(v1.w);
#pragma unroll
        for (int off = 1; off < 32; off <<= 1) s += __shfl_xor(s, off, 32);
        if ((tid & 31) == 0) atomicAdd(&racc[d], s);
      }
      __syncthreads();
    }
  }
}

// ---------------- finalize reciprocal norms ----------------
__global__ void finalize_rn(float* __restrict__ rn) {
  int i = blockIdx.x * blockDim.x + threadIdx.x;
  rn[i] = 1.f / (sqrtf(rn[i]) + 1e-5f);
}

// ---------------- feature attention (256x128 tile, BK=64, 2-phase/tile) --------
__global__ __launch_bounds__(512, 2) void attn_gemm(
    const unsigned short* __restrict__ Qt, const unsigned short* __restrict__ Kt,
    const float* __restrict__ rn, unsigned short* __restrict__ fat) {
  __shared__ __align__(16) unsigned short smem[57344];

  const int b = blockIdx.z;
  const int d0 = blockIdx.x * 128;
  const int e0 = blockIdx.y * 256;
  const unsigned short* A  = Qt + (size_t)b * DD * NSEQ;
  const unsigned short* Bm = Kt + (size_t)b * DD * NSEQ;
  unsigned short* out = fat + (size_t)b * DD * DD;

  const int tid = threadIdx.x;
  const int w = tid >> 6, lane = tid & 63;
  const int wr = w >> 1, wc = w & 1;
  const int lq = lane >> 4, lr = lane & 15;
  const int sx = lr & 7;
  const int arow0 = wr * 64 + lr;
  const int brow0 = wc * 64 + lr;

  f32x4 acc[4][4];
#pragma unroll
  for (int i = 0; i < 4; i++)
#pragma unroll
    for (int j = 0; j < 4; j++) acc[i][j] = (f32x4)(0.f);

  const int NT = 64;

  const unsigned sbase = lds_off(smem);
  const unsigned sw0 = (unsigned)((lq ^ sx) << 4);
  const unsigned sw1 = (unsigned)(((4 | lq) ^ sx) << 4);
  unsigned aA0 = sbase + arow0 * 128 + sw0;
  unsigned aA1 = sbase + arow0 * 128 + sw1;
  unsigned aB0 = sbase + 32768 + brow0 * 128 + sw0;
  unsigned aB1 = sbase + 32768 + brow0 * 128 + sw1;

  stage_half<NSEQ>(A,  e0,       0,  smem,                 tid);
  stage_half<NSEQ>(A,  e0 + 128, 0,  smem + 8192,          tid);
  stage_half<NSEQ>(Bm, d0,       0,  smem + 16384,         tid);
  stage_half<NSEQ>(Bm, d0,       64, smem + 32768 + 16384, tid);
  asm volatile("s_waitcnt vmcnt(2)" ::: "memory");
  __builtin_amdgcn_s_barrier();

  for (int t = 0; t < NT; ++t) {
    bf16x8 bfr[4][2], aL[2][2];
    DSRI(aL[0][0], aA0, 0);    DSRI(aL[0][1], aA1, 0);
    DSRI(bfr[0][0], aB0, 0);    DSRI(bfr[0][1], aB1, 0);
    DSRI(bfr[1][0], aB0, 2048); DSRI(bfr[1][1], aB1, 2048);
    DSRI(bfr[2][0], aB0, 4096); DSRI(bfr[2][1], aB1, 4096);
    DSRI(bfr[3][0], aB0, 6144); DSRI(bfr[3][1], aB1, 6144);
    DSRI(aL[1][0], aA0, 2048); DSRI(aL[1][1], aA1, 2048);
    if (t + 1 < NT) {
      stage_half<NSEQ>(A, e0,       (t + 1) * 64, smem + ((t + 1) & 1) * 32768, tid);
      stage_half<NSEQ>(A, e0 + 128, (t + 1) * 64, smem + ((t + 1) & 1) * 32768 + 8192, tid);
    }
    __builtin_amdgcn_s_barrier();
    asm volatile("s_waitcnt lgkmcnt(2)" ::: "memory");
    __builtin_amdgcn_sched_barrier(0);
    __builtin_amdgcn_s_setprio(1);
#pragma unroll
    for (int nj = 0; nj < 4; ++nj) {
      acc[0][nj] = MFMA_(aL[0][0], bfr[nj][0], acc[0][nj], 0, 0, 0);
      acc[0][nj] = MFMA_(aL[0][1], bfr[nj][1], acc[0][nj], 0, 0, 0);
    }
    asm volatile("s_waitcnt lgkmcnt(0)" ::: "memory");
    __builtin_amdgcn_sched_barrier(0);
#pragma unroll
    for (int nj = 0; nj < 4; ++nj) {
      acc[1][nj] = MFMA_(aL[1][0], bfr[nj][0], acc[1][nj], 0, 0, 0);
      acc[1][nj] = MFMA_(aL[1][1], bfr[nj][1], acc[1][nj], 0, 0, 0);
    }
    __builtin_amdgcn_s_setprio(0);
    __builtin_amdgcn_sched_barrier(0);
    __builtin_amdgcn_s_barrier();

    bf16x8 aH[2][2];
    DSRI(aH[0][0], aA0, 4096); DSRI(aH[0][1], aA1, 4096);
    DSRI(aH[1][0], aA0, 6144); DSRI(aH[1][1], aA1, 6144);
    if (t + 2 < NT) {
      stage_half<NSEQ>(Bm, d0, (t + 2) * 64, smem + (t & 1) * 32768 + 16384, tid);
    }
    __builtin_amdgcn_s_barrier();
    asm volatile("s_waitcnt lgkmcnt(2)" ::: "memory");
    __builtin_amdgcn_sched_barrier(0);
    __builtin_amdgcn_s_setprio(1);
#pragma unroll
    for (int nj = 0; nj < 4; ++nj) {
      acc[2][nj] = MFMA_(aH[0][0], bfr[nj][0], acc[2][nj], 0, 0, 0);
      acc[2][nj] = MFMA_(aH[0][1], bfr[nj][1], acc[2][nj], 0, 0, 0);
    }
    asm volatile("s_waitcnt lgkmcnt(0)" ::: "memory");
    __builtin_amdgcn_sched_barrier(0);
#pragma unroll
    for (int nj = 0; nj < 4; ++nj) {
      acc[3][nj] = MFMA_(aH[1][0], bfr[nj][0], acc[3][nj], 0, 0, 0);
      acc[3][nj] = MFMA_(aH[1][1], bfr[nj][1], acc[3][nj], 0, 0, 0);
    }
    __builtin_amdgcn_s_setprio(0);
    __builtin_amdgcn_sched_barrier(0);
    if (t < NT - 2)       asm volatile("s_waitcnt vmcnt(2)" ::: "memory");
    else if (t == NT - 2) asm volatile("s_waitcnt vmcnt(0)" ::: "memory");
    __builtin_amdgcn_s_barrier();

    aA0 ^= 65536u; aA1 ^= 65536u; aB0 ^= 65536u; aB1 ^= 65536u;
  }

#pragma unroll
  for (int nj = 0; nj < 4; ++nj) {
    int col = d0 + wc * 64 + nj * 16 + lr;
    float rk = rn[b * DD + col];
#pragma unroll
    for (int mi = 0; mi < 4; ++mi) {
      int rowb = e0 + wr * 64 + mi * 16 + lq * 4;
#pragma unroll
      for (int r = 0; r < 4; ++r) {
        float rq = rn[BB * DD + b * DD + rowb + r];
        float c = acc[mi][nj][r] * rq * rk;
        c = (c > 0.f) ? c : 0.25f * c;   // smu(mu=1e6) == leaky relu
        out[(size_t)(rowb + r) * DD + col] = f2bf(c);
      }
    }
  }
}

// ---------------- output GEMM (256^2 tile, BK=64, 2-phase/tile) ----------------
__global__ __launch_bounds__(512, 2) void out_gemm(
    const unsigned short* __restrict__ V, const unsigned short* __restrict__ fat,
    float* __restrict__ out) {
  __shared__ __align__(16) unsigned short smem[65536];

  const int bx = blockIdx.x;
  const int swz = (bx & 7) * 64 + (bx >> 3);
  const int m0 = (swz >> 2) * 256;
  const int e0 = (swz & 3) * 256;
  const int b = m0 >> 12;
  const unsigned short* Bm = fat + (size_t)b * DD * DD;

  const int tid = threadIdx.x;
  const int w = tid >> 6, lane = tid & 63;
  const int wr = w >> 2, wc = w & 3;
  const int lq = lane >> 4, lr = lane & 15;
  const int sx = lr & 7;
  const int arow0 = wr * 128 + lr;
  const int brow0 = wc * 64 + lr;

  f32x4 acc[8][4];
#pragma unroll
  for (int i = 0; i < 8; i++)
#pragma unroll
    for (int j = 0; j < 4; j++) acc[i][j] = (f32x4)(0.f);

  const int NT = 16;

  const unsigned sbase = lds_off(smem);
  const unsigned sw0 = (unsigned)((lq ^ sx) << 4);
  const unsigned sw1 = (unsigned)(((4 | lq) ^ sx) << 4);
  unsigned aA0 = sbase + arow0 * 128 + sw0;
  unsigned aA1 = sbase + arow0 * 128 + sw1;
  unsigned aB0 = sbase + 32768 + brow0 * 128 + sw0;
  unsigned aB1 = sbase + 32768 + brow0 * 128 + sw1;

  stage_half<1024>(V,  m0,       0,  smem,                        tid);
  stage_half<1024>(V,  m0 + 128, 0,  smem + 8192,                 tid);
  stage_half<1024>(Bm, e0,       0,  smem + 16384,                tid);
  stage_half<1024>(Bm, e0 + 128, 0,  smem + 16384 + 8192,         tid);
  stage_half<1024>(Bm, e0,       64, smem + 32768 + 16384,        tid);
  stage_half<1024>(Bm, e0 + 128, 64, smem + 32768 + 16384 + 8192, tid);
  asm volatile("s_waitcnt vmcnt(4)" ::: "memory");
  __builtin_amdgcn_s_barrier();

  for (int t = 0; t < NT; ++t) {
    bf16x8 bfr[4][2], aL[4][2];
    DSRI(aL[0][0], aA0, 0);    DSRI(aL[0][1], aA1, 0);
    DSRI(bfr[0][0], aB0, 0);    DSRI(bfr[0][1], aB1, 0);
    DSRI(bfr[1][0], aB0, 2048); DSRI(bfr[1][1], aB1, 2048);
    DSRI(bfr[2][0], aB0, 4096); DSRI(bfr[2][1], aB1, 4096);
    DSRI(bfr[3][0], aB0, 6144); DSRI(bfr[3][1], aB1, 6144);
    DSRI(aL[1][0], aA0, 2048); DSRI(aL[1][1], aA1, 2048);
    DSRI(aL[2][0], aA0, 4096); DSRI(aL[2][1], aA1, 4096);
    DSRI(aL[3][0], aA0, 6144); DSRI(aL[3][1], aA1, 6144);
    if (t + 1 < NT) {
      stage_half<1024>(V, m0,       (t + 1) * 64, smem + ((t + 1) & 1) * 32768, tid);
      stage_half<1024>(V, m0 + 128, (t + 1) * 64, smem + ((t + 1) & 1) * 32768 + 8192, tid);
    }
    __builtin_amdgcn_s_barrier();
    asm volatile("s_waitcnt lgkmcnt(6)" ::: "memory");
    __builtin_amdgcn_sched_barrier(0);
    __builtin_amdgcn_s_setprio(1);
#pragma unroll
    for (int nj = 0; nj < 4; ++nj) {
      acc[0][nj] = MFMA_(aL[0][0], bfr[nj][0], acc[0][nj], 0, 0, 0);
      acc[0][nj] = MFMA_(aL[0][1], bfr[nj][1], acc[0][nj], 0, 0, 0);
    }
    asm volatile("s_waitcnt lgkmcnt(0)" ::: "memory");
    __builtin_amdgcn_sched_barrier(0);
#pragma unroll
    for (int mi = 1; mi < 4; ++mi)
#pragma unroll
      for (int nj = 0; nj < 4; ++nj) {
        acc[mi][nj] = MFMA_(aL[mi][0], bfr[nj][0], acc[mi][nj], 0, 0, 0);
        acc[mi][nj] = MFMA_(aL[mi][1], bfr[nj][1], acc[mi][nj], 0, 0, 0);
      }
    __builtin_amdgcn_s_setprio(0);
    __builtin_amdgcn_sched_barrier(0);
    __builtin_amdgcn_s_barrier();

    bf16x8 aH[4][2];
    DSRI(aH[0][0], aA0, 8192);  DSRI(aH[0][1], aA1, 8192);
    DSRI(aH[1][0], aA0, 10240); DSRI(aH[1][1], aA1, 10240);
    DSRI(aH[2][0], aA0, 12288); DSRI(aH[2][1], aA1, 12288);
    DSRI(aH[3][0], aA0, 14336); DSRI(aH[3][1], aA1, 14336);
    if (t + 2 < NT) {
      stage_half<1024>(Bm, e0,       (t + 2) * 64, smem + (t & 1) * 32768 + 16384, tid);
      stage_half<1024>(Bm, e0 + 128, (t + 2) * 64, smem + (t & 1) * 32768 + 16384 + 8192, tid);
    }
    __builtin_amdgcn_s_barrier();
    asm volatile("s_waitcnt lgkmcnt(4)" ::: "memory");
    __builtin_amdgcn_sched_barrier(0);
    __builtin_amdgcn_s_setprio(1);
#pragma unroll
    for (int mi = 0; mi < 2; ++mi)
#pragma unroll
      for (int nj = 0; nj < 4; ++nj) {
        acc[4 + mi][nj] = MFMA_(aH[mi][0], bfr[nj][0], acc[4 + mi][nj], 0, 0, 0);
        acc[4 + mi][nj] = MFMA_(aH[mi][1], bfr[nj][1], acc[4 + mi][nj], 0, 0, 0);
      }
    asm volatile("s_waitcnt lgkmcnt(0)" ::: "memory");
    __builtin_amdgcn_sched_barrier(0);
#pragma unroll
    for (int mi = 2; mi < 4; ++mi)
#pragma unroll
      for (int nj = 0; nj < 4; ++nj) {
        acc[4 + mi][nj] = MFMA_(aH[mi][0], bfr[nj][0], acc[4 + mi][nj], 0, 0, 0);
        acc[4 + mi][nj] = MFMA_(aH[mi][1], bfr[nj][1], acc[4 + mi][nj], 0, 0, 0);
      }
    __builtin_amdgcn_s_setprio(0);
    __builtin_amdgcn_sched_barrier(0);
    if (t < NT - 2)       asm volatile("s_waitcnt vmcnt(4)" ::: "memory");
    else if (t == NT - 2) asm volatile("s_waitcnt vmcnt(0)" ::: "memory");
    __builtin_amdgcn_s_barrier();

    aA0 ^= 65536u; aA1 ^= 65536u; aB0 ^= 65536u; aB1 ^= 65536u;
  }

#pragma unroll
  for (int nj = 0; nj < 4; ++nj) {
    int col = e0 + wc * 64 + nj * 16 + lr;
#pragma unroll
    for (int mrep = 0; mrep < 8; ++mrep) {
      int rowb = m0 + wr * 128 + mrep * 16 + lq * 4;
#pragma unroll
      for (int r = 0; r < 4; ++r)
        out[(size_t)(rowb + r) * DD + col] = acc[mrep][nj][r];
    }
  }
}

extern "C" void kernel_launch(void* const* d_in, const int* in_sizes, int n_in,
                              void* d_out, int out_size, void* d_ws, size_t ws_size,
                              hipStream_t stream) {
  const float* x   = (const float*)d_in[0];
  const float* Wvr = (const float*)d_in[1];
  const float* bvr = (const float*)d_in[2];
  const float* Wvi = (const float*)d_in[3];
  const float* bvi = (const float*)d_in[4];
  const float* Wk  = (const float*)d_in[5];
  const float* bk  = (const float*)d_in[6];
  const float* Wq  = (const float*)d_in[7];
  const float* bq  = (const float*)d_in[8];
  float* out = (float*)d_out;

  char* p = (char*)d_ws;
  unsigned short* xb  = (unsigned short*)p; p += (size_t)MTOT * DD * 2;      // 64 MiB
  unsigned short* Wb  = (unsigned short*)p; p += 4ull * DD * DD * 2;         // 8 MiB
  unsigned short* Kt  = (unsigned short*)p; p += (size_t)BB * DD * NSEQ * 2; // 64 MiB
  unsigned short* Qt  = (unsigned short*)p; p += (size_t)BB * DD * NSEQ * 2; // 64 MiB
  unsigned short* Vb  = (unsigned short*)p; p += (size_t)MTOT * DD * 2;      // 64 MiB
  unsigned short* fat = (unsigned short*)p; p += (size_t)BB * DD * DD * 2;   // 16 MiB
  float* rn = (float*)p; p += 2ull * BB * DD * sizeof(float);                // 64 KiB

  int nx = MTOT * DD;
  int nw = DD * DD;
  cvt_bf16<<<nx / 8 / 256, 256, 0, stream>>>(x, xb, nx);
  cvt_w<<<dim3(nw / 8 / 256, 4), 256, 0, stream>>>(Wvr, Wvi, Wk, Wq, Wb);
  hipMemsetAsync(rn, 0, 2ull * BB * DD * sizeof(float), stream);

  proj_v<<<dim3(1024), 512, 0, stream>>>(xb, Wb, bvr, bvi, Vb);
  proj_kq<<<dim3(512, 1, 2), 512, 0, stream>>>(xb, Wb, bk, bq, Kt, Qt, rn);

  finalize_rn<<<2 * BB * DD / 256, 256, 0, stream>>>(rn);

  attn_gemm<<<dim3(DD / 128, DD / 256, BB), 512, 0, stream>>>(Qt, Kt, rn, fat);
  out_gemm<<<dim3(512), 512, 0, stream>>>(Vb, fat, out);
}